// Round 14
// baseline (53.375 us; speedup 1.0000x reference)
//
#include <hip/hip_runtime.h>
#include <math.h>
#include <float.h>

#define B_ 32
#define N_ 256
#define T_OBS_ 50
#define T_S_ 25
#define D_ 128
#define D_H_ 256
#define P_ 8
#define PLANE_ (T_S_ * D_)  // 3200 floats per (b,n)

static constexpr float TWO_PI_F = 6.2831854820251465f;  // float(2*pi)
static constexpr float BIN_W_F = 0.78539818525314331f;  // float32(2*pi/8)
static constexpr float EPS_F = 1e-4f;

__device__ __forceinline__ void schunk(const float* base, const float4 e,
                                       int i0, float4& m) {
#pragma unroll
  for (int i = 0; i < 8; ++i) {
    const float4 v = *(const float4*)(base + (size_t)((i0 + i) * 16) * PLANE_);
    m.x = fmaxf(m.x, e.x * v.x);
    m.y = fmaxf(m.y, e.y * v.y);
    m.z = fmaxf(m.z, e.z * v.z);
    m.w = fmaxf(m.w, e.w * v.w);
  }
}

__device__ __forceinline__ void combineA(int tid, const float4* aPart,
                                         float* sinp) {
  float4 r = aPart[tid];
#pragma unroll
  for (int g = 1; g < 16; ++g) {
    float4 v = aPart[g * 32 + tid];
    r.x = fmaxf(r.x, v.x);
    r.y = fmaxf(r.y, v.y);
    r.z = fmaxf(r.z, v.z);
    r.w = fmaxf(r.w, v.w);
  }
  *(float4*)&sinp[4 * tid] = r;
}

__device__ __forceinline__ void l1_phase(int tid, const float* W1,
                                         const float* sinp, float* pool) {
  const int s = tid >> 6, j4 = tid & 63;
  const float4* Wv = (const float4*)W1;
  float a0 = 0.f, a1 = 0.f, a2 = 0.f, a3 = 0.f;
#pragma unroll
  for (int kk = 0; kk < 16; ++kk) {
    int k = s * 16 + kk;
    float4 w = Wv[k * 64 + j4];
    float x = sinp[k];
    a0 = fmaf(x, w.x, a0);
    a1 = fmaf(x, w.y, a1);
    a2 = fmaf(x, w.z, a2);
    a3 = fmaf(x, w.w, a3);
  }
  *(float4*)&pool[s * 256 + 4 * j4] = make_float4(a0, a1, a2, a3);
}

__device__ __forceinline__ void l2_phase(int tid, const float* W2,
                                         const float* sh1, float* pool) {
  const int s = tid >> 6, j4 = tid & 63;
  const float4* Wv = (const float4*)W2;
  float a0 = 0.f, a1 = 0.f, a2 = 0.f, a3 = 0.f;
#pragma unroll
  for (int kk = 0; kk < 32; ++kk) {
    int k = s * 32 + kk;
    float4 w = Wv[k * 64 + j4];
    float x = sh1[k];
    a0 = fmaf(x, w.x, a0);
    a1 = fmaf(x, w.y, a1);
    a2 = fmaf(x, w.z, a2);
    a3 = fmaf(x, w.w, a3);
  }
  *(float4*)&pool[s * 256 + 4 * j4] = make_float4(a0, a1, a2, a3);
}

__device__ __forceinline__ void l3_phase(int tid, const float* W3,
                                         const float* sh2, float* pool) {
  const int s3 = tid >> 4, j4 = tid & 15;
  const float4* Wv = (const float4*)W3;
  float a0 = 0.f, a1 = 0.f, a2 = 0.f, a3 = 0.f;
#pragma unroll
  for (int kk = 0; kk < 8; ++kk) {
    int k = s3 * 8 + kk;
    float4 w = Wv[k * 16 + j4];
    float x = sh2[k];
    a0 = fmaf(x, w.x, a0);
    a1 = fmaf(x, w.y, a1);
    a2 = fmaf(x, w.z, a2);
    a3 = fmaf(x, w.w, a3);
  }
  *(float4*)&pool[s3 * 64 + 4 * j4] = make_float4(a0, a1, a2, a3);
}

__device__ __forceinline__ void hist_phase(int tid, int bb, int tt,
                                           const float* x_ego,
                                           const float* x_nei,
                                           float (*wh)[4][P_]) {
  const int w = tid >> 6;
  int tobs = 2 * tt;
  float2 eg = *(const float2*)&x_ego[((size_t)bb * T_OBS_ + tobs) * 2];
  float2 xn =
      *(const float2*)&x_nei[(((size_t)bb * N_ + tid) * T_OBS_ + tobs) * 2];
  float p0 = xn.x - eg.x;
  float p1 = xn.y - eg.y;
  float dist = sqrtf(p0 * p0 + p1 * p1);
  float ang = atan2f(p0, p1);
  if (ang < 0.f) ang += TWO_PI_F;
  int pidx = (int)(ang / BIN_W_F);
  bool mask = ((fabsf(p0) + fabsf(p1)) != 0.f) && (dist > 0.005f);
  if (mask && pidx >= 0 && pidx < P_) {
    atomicAdd(&wh[0][w][pidx], 1.f);
    atomicAdd(&wh[1][w][pidx], dist);
    atomicAdd(&wh[2][w][pidx], ang);
  }
}

__device__ __forceinline__ void out_phase(int tid, int bb, int tt,
                                          const float* f3s,
                                          const float (*hrow)[P_],
                                          const float* Wce, const float* bce,
                                          float* out) {
  int p = tid >> 5;
  int c0 = (tid & 31) * 4;
  float nn = hrow[0][p] + EPS_F;
  float4 v;
  if (c0 < 64) {
    float sc = hrow[0][p] / nn;
    v = make_float4(f3s[c0 + 0] * sc, f3s[c0 + 1] * sc, f3s[c0 + 2] * sc,
                    f3s[c0 + 3] * sc);
  } else {
    int jj = c0 - 64;
    float dm = hrow[1][p] / nn;
    float am = hrow[2][p] / nn;
    v.x = fmaxf(fmaf(dm, Wce[jj + 0], fmaf(am, Wce[64 + jj + 0], bce[jj + 0])), 0.f);
    v.y = fmaxf(fmaf(dm, Wce[jj + 1], fmaf(am, Wce[64 + jj + 1], bce[jj + 1])), 0.f);
    v.z = fmaxf(fmaf(dm, Wce[jj + 2], fmaf(am, Wce[64 + jj + 2], bce[jj + 2])), 0.f);
    v.w = fmaxf(fmaf(dm, Wce[jj + 3], fmaf(am, Wce[64 + jj + 3], bce[jj + 3])), 0.f);
  }
  *(float4*)(out + ((size_t)bb * T_S_ + tt) * 1024 + 4 * tid) = v;
}

// ---------------------------------------------------------------------------
// Pipelined fused kernel: 400 blocks x 512 threads; block owns rows
// (2*bid, 2*bid+1). stream(0) -> [MLP(0) || stream(1) chunks] -> MLP(1).
// ---------------------------------------------------------------------------
__global__ __launch_bounds__(512) void fused(
    const float* __restrict__ f_ego, const float* __restrict__ f_nei,
    const float* __restrict__ W1, const float* __restrict__ b1,
    const float* __restrict__ W2, const float* __restrict__ b2,
    const float* __restrict__ W3, const float* __restrict__ b3,
    const float* __restrict__ x_ego, const float* __restrict__ x_nei,
    const float* __restrict__ Wce, const float* __restrict__ bce,
    float* __restrict__ out) {
  __shared__ float4 aPart[16 * 32];  // 8 KB
  __shared__ float pool[2048];       // 8 KB
  __shared__ float sinv[2][D_];      // 1 KB
  __shared__ float sh1[D_H_];        // 1 KB
  __shared__ float sh2[D_H_];        // 1 KB
  __shared__ float f3s[64];
  __shared__ float wh[3][4][P_];     // 384 B per-wave hist {cnt,dist,ang}
  __shared__ float hrow[3][P_];      // 96 B

  const int tid = threadIdx.x;
  const int row0 = 2 * blockIdx.x;
  const int row1 = row0 + 1;
  const int ba0 = row0 / T_S_, ta0 = row0 - ba0 * T_S_;
  const int ba1 = row1 / T_S_, ta1 = row1 - ba1 * T_S_;
  const int ng = tid >> 5, d4 = tid & 31;

  if (tid < 96) (&wh[0][0][0])[tid] = 0.f;

  // ---- S0: stream item0 ----
  {
    const float4 e0 =
        *(const float4*)(f_ego + ((size_t)ba0 * T_S_ + ta0) * D_ + 4 * d4);
    const float* base0 = f_nei + (size_t)ba0 * N_ * PLANE_ +
                         (size_t)ng * PLANE_ + ta0 * D_ + 4 * d4;
    float4 m = make_float4(-FLT_MAX, -FLT_MAX, -FLT_MAX, -FLT_MAX);
    schunk(base0, e0, 0, m);
    schunk(base0, e0, 8, m);
    aPart[ng * 32 + d4] = m;
  }
  __syncthreads();  // BAR1: aPart(0) done
  if (tid < 32) combineA(tid, aPart, sinv[0]);
  __syncthreads();  // BAR2: sin(0) ready, aPart free

  // ---- steady: MLP(0) || stream(1) ----
  const float4 e1 =
      *(const float4*)(f_ego + ((size_t)ba1 * T_S_ + ta1) * D_ + 4 * d4);
  const float* base1 = f_nei + (size_t)ba1 * N_ * PLANE_ +
                       (size_t)ng * PLANE_ + ta1 * D_ + 4 * d4;
  float4 m1 = make_float4(-FLT_MAX, -FLT_MAX, -FLT_MAX, -FLT_MAX);

  schunk(base1, e1, 0, m1);  // stream chunk1(1) overlaps L1(0)
  l1_phase(tid, W1, sinv[0], pool);
  __syncthreads();  // BAR3
  schunk(base1, e1, 8, m1);  // stream chunk2(1) overlaps combine1(0)
  if (tid < 256) {
    float sum = b1[tid];
#pragma unroll
    for (int s = 0; s < 8; ++s) sum += pool[s * 256 + tid];
    sh1[tid] = fmaxf(sum, 0.f);
  }
  __syncthreads();  // BAR4: sh1 ready
  aPart[ng * 32 + d4] = m1;  // write A-partials(1) overlaps L2(0)
  l2_phase(tid, W2, sh1, pool);
  __syncthreads();  // BAR5
  if (tid < 256) {
    float sum = b2[tid];
#pragma unroll
    for (int s = 0; s < 8; ++s) sum += pool[s * 256 + tid];
    sh2[tid] = fmaxf(sum, 0.f);
  }
  __syncthreads();  // BAR6: sh2 ready
  l3_phase(tid, W3, sh2, pool);
  if (tid < 256) hist_phase(tid, ba0, ta0, x_ego, x_nei, wh);
  __syncthreads();  // BAR7: L3 partials + hist(0) done
  if (tid < 64) {
    float sum = b3[tid];
#pragma unroll
    for (int s = 0; s < 32; ++s) sum += pool[s * 64 + tid];
    f3s[tid] = fmaxf(sum, 0.f);
  } else if (tid < 88) {  // combine per-wave hist -> hrow
    int i = tid - 64;
    int which = i >> 3, p = i & 7;
    hrow[which][p] = wh[which][0][p] + wh[which][1][p] + wh[which][2][p] +
                     wh[which][3][p];
  } else if (tid >= 96 && tid < 128) {
    combineA(tid - 96, aPart, sinv[1]);  // sin(1) ready for tail
  }
  __syncthreads();  // BAR8
  if (tid < 256) out_phase(tid, ba0, ta0, f3s, hrow, Wce, bce, out);
  if (tid >= 256 && tid < 352) (&wh[0][0][0])[tid - 256] = 0.f;  // re-zero
  __syncthreads();  // BAR9

  // ---- tail: MLP(1), no stream ----
  l1_phase(tid, W1, sinv[1], pool);
  __syncthreads();  // BAR10
  if (tid < 256) {
    float sum = b1[tid];
#pragma unroll
    for (int s = 0; s < 8; ++s) sum += pool[s * 256 + tid];
    sh1[tid] = fmaxf(sum, 0.f);
  }
  __syncthreads();  // BAR11
  l2_phase(tid, W2, sh1, pool);
  __syncthreads();  // BAR12
  if (tid < 256) {
    float sum = b2[tid];
#pragma unroll
    for (int s = 0; s < 8; ++s) sum += pool[s * 256 + tid];
    sh2[tid] = fmaxf(sum, 0.f);
  }
  __syncthreads();  // BAR13
  l3_phase(tid, W3, sh2, pool);
  if (tid < 256) hist_phase(tid, ba1, ta1, x_ego, x_nei, wh);
  __syncthreads();  // BAR14
  if (tid < 64) {
    float sum = b3[tid];
#pragma unroll
    for (int s = 0; s < 32; ++s) sum += pool[s * 64 + tid];
    f3s[tid] = fmaxf(sum, 0.f);
  } else if (tid < 88) {
    int i = tid - 64;
    int which = i >> 3, p = i & 7;
    hrow[which][p] = wh[which][0][p] + wh[which][1][p] + wh[which][2][p] +
                     wh[which][3][p];
  }
  __syncthreads();  // BAR15
  if (tid < 256) out_phase(tid, ba1, ta1, f3s, hrow, Wce, bce, out);
}

// ---------------------------------------------------------------------------
extern "C" void kernel_launch(void* const* d_in, const int* in_sizes, int n_in,
                              void* d_out, int out_size, void* d_ws,
                              size_t ws_size, hipStream_t stream) {
  const float* x_ego = (const float*)d_in[0];   // (32,50,2)
  const float* x_nei = (const float*)d_in[1];   // (32,256,50,2)
  const float* f_ego = (const float*)d_in[2];   // (32,25,128)
  const float* f_nei = (const float*)d_in[3];   // (32,256,25,128)
  const float* W1 = (const float*)d_in[4];      // (128,256)
  const float* b1 = (const float*)d_in[5];
  const float* W2 = (const float*)d_in[6];      // (256,256)
  const float* b2 = (const float*)d_in[7];
  const float* W3 = (const float*)d_in[8];      // (256,64)
  const float* b3 = (const float*)d_in[9];
  const float* Wce = (const float*)d_in[10];    // (2,64)
  const float* bce = (const float*)d_in[11];
  float* out = (float*)d_out;                   // (32,25,8,128)

  fused<<<(B_ * T_S_) / 2, 512, 0, stream>>>(f_ego, f_nei, W1, b1, W2, b2, W3,
                                             b3, x_ego, x_nei, Wce, bce, out);
}

// Round 15
// 33.037 us; speedup vs baseline: 1.6156x; 1.6156x over previous
//
#include <hip/hip_runtime.h>
#include <math.h>
#include <float.h>

#define B_ 32
#define N_ 256
#define T_OBS_ 50
#define T_S_ 25
#define D_ 128
#define D_H_ 256
#define P_ 8
#define PLANE_ (T_S_ * D_)  // 3200 floats per (b,n)
#define TQ_ 7               // t-quads per batch (6 full + clamped last)

static constexpr float TWO_PI_F = 6.2831854820251465f;  // float(2*pi)
static constexpr float BIN_W_F = 0.78539818525314331f;  // float32(2*pi/8)
static constexpr float EPS_F = 1e-4f;

// ---------------------------------------------------------------------------
// Fused kernel, t-quad (RB4): 224 blocks x 512 threads; block owns rows
// 4q..4q+3 of batch b (clamped to 24). Phase A: stream f_nei for the 4 rows
// (wave reads 1KB contiguous; 64 indep loads/thread). MLP: each weight float4
// feeds 16 FMAs (4 rows x 4 cols) -> weight L2 traffic halves vs t-pair.
// ---------------------------------------------------------------------------
__global__ __launch_bounds__(512) void fused(
    const float* __restrict__ f_ego, const float* __restrict__ f_nei,
    const float* __restrict__ W1, const float* __restrict__ b1,
    const float* __restrict__ W2, const float* __restrict__ b2,
    const float* __restrict__ W3, const float* __restrict__ b3,
    const float* __restrict__ x_ego, const float* __restrict__ x_nei,
    const float* __restrict__ Wce, const float* __restrict__ bce,
    float* __restrict__ out) {
  __shared__ float spool[8192];   // 32 KB: A-partials (first 8 KB), k-slices
  __shared__ float sinv[4][D_];   // 2 KB
  __shared__ float sh1[4][D_H_];  // 4 KB
  __shared__ float sh2[4][D_H_];  // 4 KB
  __shared__ float f3s[4][64];    // 1 KB
  __shared__ float cnt[4][P_], dsum[4][P_], asum[4][P_];  // 384 B

  const int tid = threadIdx.x;
  const int b = blockIdx.x / TQ_;
  const int q = blockIdx.x - b * TQ_;

  if (tid < 96) {
    (&cnt[0][0])[tid < 32 ? tid : tid] = 0.f;  // flatten: 3 arrays x 32
  }
  // simpler explicit zero (3*32 = 96 floats laid out contiguously):
  if (tid < 32) (&cnt[0][0])[tid] = 0.f;
  else if (tid < 64) (&dsum[0][0])[tid - 32] = 0.f;
  else if (tid < 96) (&asum[0][0])[tid - 64] = 0.f;

  // ---- phase A: sub = tid&127 -> (lt = sub>>5 row-in-quad, d4 = sub&31);
  //      ng = tid>>7 (4 n-groups); n = ng + 4*i, i = 0..63 ----
  {
    const int sub = tid & 127;
    const int ng = tid >> 7;
    const int lt = sub >> 5;
    const int d4 = sub & 31;
    int t = 4 * q + lt;
    if (t > T_S_ - 1) t = T_S_ - 1;
    const float4 e =
        *(const float4*)(f_ego + ((size_t)b * T_S_ + t) * D_ + 4 * d4);
    const float* base = f_nei + (size_t)b * N_ * PLANE_ + t * D_ + 4 * d4;
    float4 m = make_float4(-FLT_MAX, -FLT_MAX, -FLT_MAX, -FLT_MAX);
#pragma unroll 16
    for (int i = 0; i < 64; ++i) {
      int n = ng + 4 * i;
      float4 v = *(const float4*)(base + (size_t)n * PLANE_);
      m.x = fmaxf(m.x, e.x * v.x);
      m.y = fmaxf(m.y, e.y * v.y);
      m.z = fmaxf(m.z, e.z * v.z);
      m.w = fmaxf(m.w, e.w * v.w);
    }
    ((float4*)spool)[ng * 128 + sub] = m;
  }

  // ---- histogram input loads, hoisted (2 items/thread, static regs) ----
  float2 eg0, xn0, eg1, xn1;
  {
    int r0 = tid >> 8, n0 = tid & 255;
    int ta = 4 * q + r0;
    if (ta > T_S_ - 1) ta = T_S_ - 1;
    int tobs = 2 * ta;
    eg0 = *(const float2*)&x_ego[((size_t)b * T_OBS_ + tobs) * 2];
    xn0 = *(const float2*)&x_nei[(((size_t)b * N_ + n0) * T_OBS_ + tobs) * 2];
    int i2 = tid + 512;
    int r1 = i2 >> 8, n1 = i2 & 255;
    int tb = 4 * q + r1;
    if (tb > T_S_ - 1) tb = T_S_ - 1;
    int tobs1 = 2 * tb;
    eg1 = *(const float2*)&x_ego[((size_t)b * T_OBS_ + tobs1) * 2];
    xn1 = *(const float2*)&x_nei[(((size_t)b * N_ + n1) * T_OBS_ + tobs1) * 2];
  }
  __syncthreads();  // B0: A-partials done

  // ---- combine A: 128 threads reduce 4 n-groups -> sinv ----
  if (tid < 128) {
    const float4* aPart = (const float4*)spool;
    float4 r = aPart[tid];
#pragma unroll
    for (int g = 1; g < 4; ++g) {
      float4 v = aPart[g * 128 + tid];
      r.x = fmaxf(r.x, v.x);
      r.y = fmaxf(r.y, v.y);
      r.z = fmaxf(r.z, v.z);
      r.w = fmaxf(r.w, v.w);
    }
    *(float4*)&sinv[tid >> 5][4 * (tid & 31)] = r;
  }
  __syncthreads();  // B1: sinv ready, spool free

  // ---- layer 1: 128 -> 256. s=tid>>6 (8 slices of 16 k), j4=tid&63 ----
  {
    const int s = tid >> 6, j4 = tid & 63;
    const float4* Wv = (const float4*)W1;
    float a0[4], a1[4], a2[4], a3[4];
#pragma unroll
    for (int r = 0; r < 4; ++r) a0[r] = a1[r] = a2[r] = a3[r] = 0.f;
#pragma unroll
    for (int kk = 0; kk < 16; ++kk) {
      int k = s * 16 + kk;
      float4 w = Wv[k * 64 + j4];
#pragma unroll
      for (int r = 0; r < 4; ++r) {
        float x = sinv[r][k];
        a0[r] = fmaf(x, w.x, a0[r]);
        a1[r] = fmaf(x, w.y, a1[r]);
        a2[r] = fmaf(x, w.z, a2[r]);
        a3[r] = fmaf(x, w.w, a3[r]);
      }
    }
#pragma unroll
    for (int r = 0; r < 4; ++r)
      *(float4*)&spool[(s * 4 + r) * 256 + 4 * j4] =
          make_float4(a0[r], a1[r], a2[r], a3[r]);
  }
  __syncthreads();  // B2
  {  // combine1: 1024 outputs, 2 per thread
#pragma unroll
    for (int rep = 0; rep < 2; ++rep) {
      int idx = tid + rep * 512;
      int r = idx >> 8, j = idx & 255;
      float sum = b1[j];
#pragma unroll
      for (int s = 0; s < 8; ++s) sum += spool[(s * 4 + r) * 256 + j];
      sh1[r][j] = fmaxf(sum, 0.f);
    }
  }
  __syncthreads();  // B3: sh1 ready

  // ---- layer 2: 256 -> 256. 8 slices of 32 k ----
  {
    const int s = tid >> 6, j4 = tid & 63;
    const float4* Wv = (const float4*)W2;
    float a0[4], a1[4], a2[4], a3[4];
#pragma unroll
    for (int r = 0; r < 4; ++r) a0[r] = a1[r] = a2[r] = a3[r] = 0.f;
#pragma unroll
    for (int kk = 0; kk < 32; ++kk) {
      int k = s * 32 + kk;
      float4 w = Wv[k * 64 + j4];
#pragma unroll
      for (int r = 0; r < 4; ++r) {
        float x = sh1[r][k];
        a0[r] = fmaf(x, w.x, a0[r]);
        a1[r] = fmaf(x, w.y, a1[r]);
        a2[r] = fmaf(x, w.z, a2[r]);
        a3[r] = fmaf(x, w.w, a3[r]);
      }
    }
#pragma unroll
    for (int r = 0; r < 4; ++r)
      *(float4*)&spool[(s * 4 + r) * 256 + 4 * j4] =
          make_float4(a0[r], a1[r], a2[r], a3[r]);
  }
  __syncthreads();  // B4
  {  // combine2
#pragma unroll
    for (int rep = 0; rep < 2; ++rep) {
      int idx = tid + rep * 512;
      int r = idx >> 8, j = idx & 255;
      float sum = b2[j];
#pragma unroll
      for (int s = 0; s < 8; ++s) sum += spool[(s * 4 + r) * 256 + j];
      sh2[r][j] = fmaxf(sum, 0.f);
    }
  }
  __syncthreads();  // B5: sh2 ready, spool free

  // ---- layer 3: 256 -> 64. s3=tid>>4 (32 slices of 8 k), j4=tid&15;
  //      plus histogram math + LDS atomics (2 items/thread) ----
  {
    const int s3 = tid >> 4, j4 = tid & 15;
    const float4* Wv = (const float4*)W3;
    float a0[4], a1[4], a2[4], a3[4];
#pragma unroll
    for (int r = 0; r < 4; ++r) a0[r] = a1[r] = a2[r] = a3[r] = 0.f;
#pragma unroll
    for (int kk = 0; kk < 8; ++kk) {
      int k = s3 * 8 + kk;
      float4 w = Wv[k * 16 + j4];
#pragma unroll
      for (int r = 0; r < 4; ++r) {
        float x = sh2[r][k];
        a0[r] = fmaf(x, w.x, a0[r]);
        a1[r] = fmaf(x, w.y, a1[r]);
        a2[r] = fmaf(x, w.z, a2[r]);
        a3[r] = fmaf(x, w.w, a3[r]);
      }
    }
#pragma unroll
    for (int r = 0; r < 4; ++r)
      *(float4*)&spool[(s3 * 4 + r) * 64 + 4 * j4] =
          make_float4(a0[r], a1[r], a2[r], a3[r]);
  }
  {
    // item 0
    int r0 = tid >> 8;
    float p0 = xn0.x - eg0.x;
    float p1 = xn0.y - eg0.y;
    float dist = sqrtf(p0 * p0 + p1 * p1);
    float ang = atan2f(p0, p1);
    if (ang < 0.f) ang += TWO_PI_F;
    int pidx = (int)(ang / BIN_W_F);
    bool mask = ((fabsf(p0) + fabsf(p1)) != 0.f) && (dist > 0.005f);
    if (mask && pidx >= 0 && pidx < P_) {
      atomicAdd(&cnt[r0][pidx], 1.f);
      atomicAdd(&dsum[r0][pidx], dist);
      atomicAdd(&asum[r0][pidx], ang);
    }
    // item 1
    int r1 = (tid + 512) >> 8;
    float q0 = xn1.x - eg1.x;
    float q1 = xn1.y - eg1.y;
    float dist2 = sqrtf(q0 * q0 + q1 * q1);
    float ang2 = atan2f(q0, q1);
    if (ang2 < 0.f) ang2 += TWO_PI_F;
    int pidx2 = (int)(ang2 / BIN_W_F);
    bool mask2 = ((fabsf(q0) + fabsf(q1)) != 0.f) && (dist2 > 0.005f);
    if (mask2 && pidx2 >= 0 && pidx2 < P_) {
      atomicAdd(&cnt[r1][pidx2], 1.f);
      atomicAdd(&dsum[r1][pidx2], dist2);
      atomicAdd(&asum[r1][pidx2], ang2);
    }
  }
  __syncthreads();  // B6: layer3 partials + histogram done

  if (tid < 256) {  // combine3 -> f3s
    int r = tid >> 6, j = tid & 63;
    float sum = b3[j];
#pragma unroll
    for (int s = 0; s < 32; ++s) sum += spool[(s * 4 + r) * 64 + j];
    f3s[r][j] = fmaxf(sum, 0.f);
  }
  __syncthreads();  // B7: f3s ready

  // ---- output: 4 rows x 256 float4 = 1024 stores, 2 per thread ----
  {
#pragma unroll
    for (int rep = 0; rep < 2; ++rep) {
      int idx = tid + rep * 512;
      int r = idx >> 8, i4 = idx & 255;
      int t = 4 * q + r;
      if (t > T_S_ - 1) t = T_S_ - 1;
      int p = i4 >> 5;
      int c0 = (i4 & 31) * 4;
      float nn = cnt[r][p] + EPS_F;
      float4 v;
      if (c0 < 64) {
        float sc = cnt[r][p] / nn;
        v = make_float4(f3s[r][c0 + 0] * sc, f3s[r][c0 + 1] * sc,
                        f3s[r][c0 + 2] * sc, f3s[r][c0 + 3] * sc);
      } else {
        int jj = c0 - 64;
        float dm = dsum[r][p] / nn;
        float am = asum[r][p] / nn;
        v.x = fmaxf(fmaf(dm, Wce[jj + 0], fmaf(am, Wce[64 + jj + 0], bce[jj + 0])), 0.f);
        v.y = fmaxf(fmaf(dm, Wce[jj + 1], fmaf(am, Wce[64 + jj + 1], bce[jj + 1])), 0.f);
        v.z = fmaxf(fmaf(dm, Wce[jj + 2], fmaf(am, Wce[64 + jj + 2], bce[jj + 2])), 0.f);
        v.w = fmaxf(fmaf(dm, Wce[jj + 3], fmaf(am, Wce[64 + jj + 3], bce[jj + 3])), 0.f);
      }
      *(float4*)(out + ((size_t)b * T_S_ + t) * 1024 + 4 * i4) = v;
    }
  }
}

// ---------------------------------------------------------------------------
extern "C" void kernel_launch(void* const* d_in, const int* in_sizes, int n_in,
                              void* d_out, int out_size, void* d_ws,
                              size_t ws_size, hipStream_t stream) {
  const float* x_ego = (const float*)d_in[0];   // (32,50,2)
  const float* x_nei = (const float*)d_in[1];   // (32,256,50,2)
  const float* f_ego = (const float*)d_in[2];   // (32,25,128)
  const float* f_nei = (const float*)d_in[3];   // (32,256,25,128)
  const float* W1 = (const float*)d_in[4];      // (128,256)
  const float* b1 = (const float*)d_in[5];
  const float* W2 = (const float*)d_in[6];      // (256,256)
  const float* b2 = (const float*)d_in[7];
  const float* W3 = (const float*)d_in[8];      // (256,64)
  const float* b3 = (const float*)d_in[9];
  const float* Wce = (const float*)d_in[10];    // (2,64)
  const float* bce = (const float*)d_in[11];
  float* out = (float*)d_out;                   // (32,25,8,128)

  fused<<<B_ * TQ_, 512, 0, stream>>>(f_ego, f_nei, W1, b1, W2, b2, W3, b3,
                                      x_ego, x_nei, Wce, bce, out);
}

// Round 16
// 32.525 us; speedup vs baseline: 1.6410x; 1.0157x over previous
//
#include <hip/hip_runtime.h>
#include <math.h>
#include <float.h>

#define B_ 32
#define N_ 256
#define T_OBS_ 50
#define T_S_ 25
#define D_ 128
#define D_H_ 256
#define P_ 8
#define PLANE_ (T_S_ * D_)  // 3200 floats per (b,n)
#define TQ_ 7               // t-quads per batch (6 full + clamped last)

static constexpr float TWO_PI_F = 6.2831854820251465f;  // float(2*pi)
static constexpr float BIN_W_F = 0.78539818525314331f;  // float32(2*pi/8)
static constexpr float EPS_F = 1e-4f;

// ---------------------------------------------------------------------------
// Fused kernel, t-quad (RB4): 224 blocks x 512 threads (R15 winner) with
// deeper memory pipelining: launch_bounds(512,2) frees VGPRs; phase A issues
// 8 independent float4 loads per batch with dual max accumulators; W1 is
// prefetched to registers before phase A (independent of the stream).
// ---------------------------------------------------------------------------
__global__ __launch_bounds__(512, 2) void fused(
    const float* __restrict__ f_ego, const float* __restrict__ f_nei,
    const float* __restrict__ W1, const float* __restrict__ b1,
    const float* __restrict__ W2, const float* __restrict__ b2,
    const float* __restrict__ W3, const float* __restrict__ b3,
    const float* __restrict__ x_ego, const float* __restrict__ x_nei,
    const float* __restrict__ Wce, const float* __restrict__ bce,
    float* __restrict__ out) {
  __shared__ float spool[8192];   // 32 KB: A-partials (first 8 KB), k-slices
  __shared__ float sinv[4][D_];   // 2 KB
  __shared__ float sh1[4][D_H_];  // 4 KB
  __shared__ float sh2[4][D_H_];  // 4 KB
  __shared__ float f3s[4][64];    // 1 KB
  __shared__ float cnt[4][P_], dsum[4][P_], asum[4][P_];  // 384 B

  const int tid = threadIdx.x;
  const int b = blockIdx.x / TQ_;
  const int q = blockIdx.x - b * TQ_;

  if (tid < 32) (&cnt[0][0])[tid] = 0.f;
  else if (tid < 64) (&dsum[0][0])[tid - 32] = 0.f;
  else if (tid < 96) (&asum[0][0])[tid - 64] = 0.f;

  // ---- W1 prefetch into registers (consumed in layer 1) ----
  const int s_l1 = tid >> 6, j4_l1 = tid & 63;
  float4 w1r[16];
  {
    const float4* Wv = (const float4*)W1;
#pragma unroll
    for (int kk = 0; kk < 16; ++kk)
      w1r[kk] = Wv[(s_l1 * 16 + kk) * 64 + j4_l1];
  }

  // ---- histogram input loads, hoisted (2 items/thread, static regs) ----
  float2 eg0, xn0, eg1, xn1;
  {
    int r0 = tid >> 8, n0 = tid & 255;
    int ta = 4 * q + r0;
    if (ta > T_S_ - 1) ta = T_S_ - 1;
    int tobs = 2 * ta;
    eg0 = *(const float2*)&x_ego[((size_t)b * T_OBS_ + tobs) * 2];
    xn0 = *(const float2*)&x_nei[(((size_t)b * N_ + n0) * T_OBS_ + tobs) * 2];
    int i2 = tid + 512;
    int r1 = i2 >> 8, n1 = i2 & 255;
    int tb = 4 * q + r1;
    if (tb > T_S_ - 1) tb = T_S_ - 1;
    int tobs1 = 2 * tb;
    eg1 = *(const float2*)&x_ego[((size_t)b * T_OBS_ + tobs1) * 2];
    xn1 = *(const float2*)&x_nei[(((size_t)b * N_ + n1) * T_OBS_ + tobs1) * 2];
  }

  // ---- phase A: sub = tid&127 -> (lt row-in-quad, d4); ng = tid>>7;
  //      n = ng + 4*i; 8 batches x 8-deep independent loads ----
  {
    const int sub = tid & 127;
    const int ng = tid >> 7;
    const int lt = sub >> 5;
    const int d4 = sub & 31;
    int t = 4 * q + lt;
    if (t > T_S_ - 1) t = T_S_ - 1;
    const float4 e =
        *(const float4*)(f_ego + ((size_t)b * T_S_ + t) * D_ + 4 * d4);
    const float* base = f_nei + (size_t)b * N_ * PLANE_ + t * D_ + 4 * d4;
    float4 m0 = make_float4(-FLT_MAX, -FLT_MAX, -FLT_MAX, -FLT_MAX);
    float4 m1 = m0;
#pragma unroll
    for (int i0 = 0; i0 < 64; i0 += 8) {
      float4 v[8];
#pragma unroll
      for (int i = 0; i < 8; ++i)
        v[i] = *(const float4*)(base + (size_t)((ng + 4 * (i0 + i)) * PLANE_));
#pragma unroll
      for (int i = 0; i < 8; i += 2) {
        m0.x = fmaxf(m0.x, e.x * v[i].x);
        m0.y = fmaxf(m0.y, e.y * v[i].y);
        m0.z = fmaxf(m0.z, e.z * v[i].z);
        m0.w = fmaxf(m0.w, e.w * v[i].w);
        m1.x = fmaxf(m1.x, e.x * v[i + 1].x);
        m1.y = fmaxf(m1.y, e.y * v[i + 1].y);
        m1.z = fmaxf(m1.z, e.z * v[i + 1].z);
        m1.w = fmaxf(m1.w, e.w * v[i + 1].w);
      }
    }
    m0.x = fmaxf(m0.x, m1.x);
    m0.y = fmaxf(m0.y, m1.y);
    m0.z = fmaxf(m0.z, m1.z);
    m0.w = fmaxf(m0.w, m1.w);
    ((float4*)spool)[ng * 128 + sub] = m0;
  }
  __syncthreads();  // B0: A-partials done

  // ---- combine A: 128 threads reduce 4 n-groups -> sinv ----
  if (tid < 128) {
    const float4* aPart = (const float4*)spool;
    float4 r = aPart[tid];
#pragma unroll
    for (int g = 1; g < 4; ++g) {
      float4 v = aPart[g * 128 + tid];
      r.x = fmaxf(r.x, v.x);
      r.y = fmaxf(r.y, v.y);
      r.z = fmaxf(r.z, v.z);
      r.w = fmaxf(r.w, v.w);
    }
    *(float4*)&sinv[tid >> 5][4 * (tid & 31)] = r;
  }
  __syncthreads();  // B1: sinv ready, spool free

  // ---- layer 1: 128 -> 256 using prefetched w1r ----
  {
    float a0[4], a1[4], a2[4], a3[4];
#pragma unroll
    for (int r = 0; r < 4; ++r) a0[r] = a1[r] = a2[r] = a3[r] = 0.f;
#pragma unroll
    for (int kk = 0; kk < 16; ++kk) {
      int k = s_l1 * 16 + kk;
      float4 w = w1r[kk];
#pragma unroll
      for (int r = 0; r < 4; ++r) {
        float x = sinv[r][k];
        a0[r] = fmaf(x, w.x, a0[r]);
        a1[r] = fmaf(x, w.y, a1[r]);
        a2[r] = fmaf(x, w.z, a2[r]);
        a3[r] = fmaf(x, w.w, a3[r]);
      }
    }
#pragma unroll
    for (int r = 0; r < 4; ++r)
      *(float4*)&spool[(s_l1 * 4 + r) * 256 + 4 * j4_l1] =
          make_float4(a0[r], a1[r], a2[r], a3[r]);
  }
  __syncthreads();  // B2
  {  // combine1: 1024 outputs, 2 per thread
#pragma unroll
    for (int rep = 0; rep < 2; ++rep) {
      int idx = tid + rep * 512;
      int r = idx >> 8, j = idx & 255;
      float sum = b1[j];
#pragma unroll
      for (int s = 0; s < 8; ++s) sum += spool[(s * 4 + r) * 256 + j];
      sh1[r][j] = fmaxf(sum, 0.f);
    }
  }
  __syncthreads();  // B3: sh1 ready

  // ---- layer 2: 256 -> 256. 8 slices of 32 k ----
  {
    const int s = tid >> 6, j4 = tid & 63;
    const float4* Wv = (const float4*)W2;
    float a0[4], a1[4], a2[4], a3[4];
#pragma unroll
    for (int r = 0; r < 4; ++r) a0[r] = a1[r] = a2[r] = a3[r] = 0.f;
#pragma unroll
    for (int kk = 0; kk < 32; ++kk) {
      int k = s * 32 + kk;
      float4 w = Wv[k * 64 + j4];
#pragma unroll
      for (int r = 0; r < 4; ++r) {
        float x = sh1[r][k];
        a0[r] = fmaf(x, w.x, a0[r]);
        a1[r] = fmaf(x, w.y, a1[r]);
        a2[r] = fmaf(x, w.z, a2[r]);
        a3[r] = fmaf(x, w.w, a3[r]);
      }
    }
#pragma unroll
    for (int r = 0; r < 4; ++r)
      *(float4*)&spool[(s * 4 + r) * 256 + 4 * j4] =
          make_float4(a0[r], a1[r], a2[r], a3[r]);
  }
  __syncthreads();  // B4
  {  // combine2
#pragma unroll
    for (int rep = 0; rep < 2; ++rep) {
      int idx = tid + rep * 512;
      int r = idx >> 8, j = idx & 255;
      float sum = b2[j];
#pragma unroll
      for (int s = 0; s < 8; ++s) sum += spool[(s * 4 + r) * 256 + j];
      sh2[r][j] = fmaxf(sum, 0.f);
    }
  }
  __syncthreads();  // B5: sh2 ready, spool free

  // ---- layer 3: 256 -> 64. 32 slices of 8 k; plus histogram ----
  {
    const int s3 = tid >> 4, j4 = tid & 15;
    const float4* Wv = (const float4*)W3;
    float a0[4], a1[4], a2[4], a3[4];
#pragma unroll
    for (int r = 0; r < 4; ++r) a0[r] = a1[r] = a2[r] = a3[r] = 0.f;
#pragma unroll
    for (int kk = 0; kk < 8; ++kk) {
      int k = s3 * 8 + kk;
      float4 w = Wv[k * 16 + j4];
#pragma unroll
      for (int r = 0; r < 4; ++r) {
        float x = sh2[r][k];
        a0[r] = fmaf(x, w.x, a0[r]);
        a1[r] = fmaf(x, w.y, a1[r]);
        a2[r] = fmaf(x, w.z, a2[r]);
        a3[r] = fmaf(x, w.w, a3[r]);
      }
    }
#pragma unroll
    for (int r = 0; r < 4; ++r)
      *(float4*)&spool[(s3 * 4 + r) * 64 + 4 * j4] =
          make_float4(a0[r], a1[r], a2[r], a3[r]);
  }
  {
    // item 0
    int r0 = tid >> 8;
    float p0 = xn0.x - eg0.x;
    float p1 = xn0.y - eg0.y;
    float dist = sqrtf(p0 * p0 + p1 * p1);
    float ang = atan2f(p0, p1);
    if (ang < 0.f) ang += TWO_PI_F;
    int pidx = (int)(ang / BIN_W_F);
    bool mask = ((fabsf(p0) + fabsf(p1)) != 0.f) && (dist > 0.005f);
    if (mask && pidx >= 0 && pidx < P_) {
      atomicAdd(&cnt[r0][pidx], 1.f);
      atomicAdd(&dsum[r0][pidx], dist);
      atomicAdd(&asum[r0][pidx], ang);
    }
    // item 1
    int r1 = (tid + 512) >> 8;
    float q0 = xn1.x - eg1.x;
    float q1 = xn1.y - eg1.y;
    float dist2 = sqrtf(q0 * q0 + q1 * q1);
    float ang2 = atan2f(q0, q1);
    if (ang2 < 0.f) ang2 += TWO_PI_F;
    int pidx2 = (int)(ang2 / BIN_W_F);
    bool mask2 = ((fabsf(q0) + fabsf(q1)) != 0.f) && (dist2 > 0.005f);
    if (mask2 && pidx2 >= 0 && pidx2 < P_) {
      atomicAdd(&cnt[r1][pidx2], 1.f);
      atomicAdd(&dsum[r1][pidx2], dist2);
      atomicAdd(&asum[r1][pidx2], ang2);
    }
  }
  __syncthreads();  // B6: layer3 partials + histogram done

  if (tid < 256) {  // combine3 -> f3s
    int r = tid >> 6, j = tid & 63;
    float sum = b3[j];
#pragma unroll
    for (int s = 0; s < 32; ++s) sum += spool[(s * 4 + r) * 64 + j];
    f3s[r][j] = fmaxf(sum, 0.f);
  }
  __syncthreads();  // B7: f3s ready

  // ---- output: 4 rows x 256 float4 = 1024 stores, 2 per thread ----
  {
#pragma unroll
    for (int rep = 0; rep < 2; ++rep) {
      int idx = tid + rep * 512;
      int r = idx >> 8, i4 = idx & 255;
      int t = 4 * q + r;
      if (t > T_S_ - 1) t = T_S_ - 1;
      int p = i4 >> 5;
      int c0 = (i4 & 31) * 4;
      float nn = cnt[r][p] + EPS_F;
      float4 v;
      if (c0 < 64) {
        float sc = cnt[r][p] / nn;
        v = make_float4(f3s[r][c0 + 0] * sc, f3s[r][c0 + 1] * sc,
                        f3s[r][c0 + 2] * sc, f3s[r][c0 + 3] * sc);
      } else {
        int jj = c0 - 64;
        float dm = dsum[r][p] / nn;
        float am = asum[r][p] / nn;
        v.x = fmaxf(fmaf(dm, Wce[jj + 0], fmaf(am, Wce[64 + jj + 0], bce[jj + 0])), 0.f);
        v.y = fmaxf(fmaf(dm, Wce[jj + 1], fmaf(am, Wce[64 + jj + 1], bce[jj + 1])), 0.f);
        v.z = fmaxf(fmaf(dm, Wce[jj + 2], fmaf(am, Wce[64 + jj + 2], bce[jj + 2])), 0.f);
        v.w = fmaxf(fmaf(dm, Wce[jj + 3], fmaf(am, Wce[64 + jj + 3], bce[jj + 3])), 0.f);
      }
      *(float4*)(out + ((size_t)b * T_S_ + t) * 1024 + 4 * i4) = v;
    }
  }
}

// ---------------------------------------------------------------------------
extern "C" void kernel_launch(void* const* d_in, const int* in_sizes, int n_in,
                              void* d_out, int out_size, void* d_ws,
                              size_t ws_size, hipStream_t stream) {
  const float* x_ego = (const float*)d_in[0];   // (32,50,2)
  const float* x_nei = (const float*)d_in[1];   // (32,256,50,2)
  const float* f_ego = (const float*)d_in[2];   // (32,25,128)
  const float* f_nei = (const float*)d_in[3];   // (32,256,25,128)
  const float* W1 = (const float*)d_in[4];      // (128,256)
  const float* b1 = (const float*)d_in[5];
  const float* W2 = (const float*)d_in[6];      // (256,256)
  const float* b2 = (const float*)d_in[7];
  const float* W3 = (const float*)d_in[8];      // (256,64)
  const float* b3 = (const float*)d_in[9];
  const float* Wce = (const float*)d_in[10];    // (2,64)
  const float* bce = (const float*)d_in[11];
  float* out = (float*)d_out;                   // (32,25,8,128)

  fused<<<B_ * TQ_, 512, 0, stream>>>(f_ego, f_nei, W1, b1, W2, b2, W3, b3,
                                      x_ego, x_nei, Wce, bce, out);
}